// Round 1
// baseline (537.079 us; speedup 1.0000x reference)
//
#include <hip/hip_runtime.h>
#include <cstdint>
#include <cstddef>

// Problem constants
#define H_   4096
#define D_   1024
#define A_   512
#define B_   4
#define LQ_  2048
#define TM_  1500
#define TMP_ 1536   // TM padded to multiple of 128
#define EPS_ 1e-5f

typedef __attribute__((ext_vector_type(8))) _Float16 half8;
typedef __attribute__((ext_vector_type(4))) _Float16 half4v;
typedef __attribute__((ext_vector_type(4))) float f32x4;

// ---------------------------------------------------------------- helpers
__device__ __forceinline__ void gload_lds16(void* g, void* l) {
  // async global->LDS, 16B per lane; LDS dest = wave-uniform base + lane*16
  __builtin_amdgcn_global_load_lds((__attribute__((address_space(1))) void*)g,
                                   (__attribute__((address_space(3))) void*)l,
                                   16, 0, 0);
}

// ---------------------------------------------------------------- core 128x128 MFMA tile
// C[m][n] = scale * sum_k A[m][k] * Bt[n][k] (+ bias[n])
// OUTMODE: 0 = f16 row-major, 1 = f16 transposed (C[n][m], packed 8B stores),
//          2 = fp32 row-major (no bias), 3 = exp-scores: write f16 exp(v*scale)
//              with mask/pad zeroing + per-row atomic sums into lsum.
// LDS chunk swizzle: global 16B chunk (cs ^ ((r>>1)&3)) lands in LDS slot cs ->
// reader slot j^((rsub>>1)&3); 0 bank conflicts measured (R2).
// R(dbuf): double-buffered LDS, ONE barrier per K-step; next tile's
// global_load_lds issued BEFORE current tile's ds_read+MFMA so the staging
// latency overlaps compute (T3-minimum 2-phase). kiters must be EVEN
// (all call sites: 16/32/64).
template <int OUTMODE>
__device__ __forceinline__ void gemm_tile(
    const _Float16* __restrict__ A, int lda,
    const _Float16* __restrict__ Bt, int ldb,
    const float* __restrict__ bias,
    void* __restrict__ C, int ldc,
    int Mvalid, int m0, int n0, int kbase, int kiters, float scale,
    _Float16* As, _Float16* Bs,   // each 2*4096 f16 (double-buffered)
    const unsigned char* __restrict__ mrow, float* __restrict__ lsum, int nvalid) {
  const int tid = threadIdx.x;
  const int lane = tid & 63;
  const int wave = tid >> 6;

  f32x4 acc[4][4];
#pragma unroll
  for (int i = 0; i < 4; ++i)
#pragma unroll
    for (int jj = 0; jj < 4; ++jj) acc[i][jj] = (f32x4){0.f, 0.f, 0.f, 0.f};

  // staging: 128x32 f16 tile = 512 chunks of 16B; 256 threads x 2 chunks each
  const _Float16* gA[2];
  const _Float16* gB[2];
  _Float16* lA[2];
  _Float16* lB[2];
#pragma unroll
  for (int i = 0; i < 2; ++i) {
    const int c = wave * 64 + lane + 256 * i;
    const int r = c >> 2;
    const int cs = c & 3;
    const int col = (cs ^ ((r >> 1) & 3)) * 8;  // XOR-swizzled 16B chunk
    int ra = m0 + r;
    if (ra >= Mvalid) ra = Mvalid - 1;  // clamp (pad rows dup last valid row)
    gA[i] = A + (size_t)ra * lda + kbase + col;
    gB[i] = Bt + (size_t)(n0 + r) * ldb + kbase + col;
    lA[i] = As + wave * 512 + i * 2048;  // wave-uniform LDS base (buf 0)
    lB[i] = Bs + wave * 512 + i * 2048;
  }

  const int wm = (wave >> 1) * 64;
  const int wn = (wave & 1) * 64;
  const int rsub = lane & 15;
  const int j = lane >> 4;                 // which 16B chunk of the 32-wide K row
  const int slot = j ^ ((rsub >> 1) & 3);  // swizzled LDS slot (constant per lane)

  auto stage = [&](int buf, int kt) {
    const int ko = kt * 32;
#pragma unroll
    for (int i = 0; i < 2; ++i) {
      gload_lds16((void*)(gA[i] + ko), (void*)(lA[i] + buf * 4096));
      gload_lds16((void*)(gB[i] + ko), (void*)(lB[i] + buf * 4096));
    }
  };
  auto compute = [&](int buf) {
    const _Float16* Ab = As + buf * 4096;
    const _Float16* Bb = Bs + buf * 4096;
    half8 af[4], bfr[4];
#pragma unroll
    for (int x = 0; x < 4; ++x) {
      af[x]  = *(const half8*)&Ab[(wm + x * 16 + rsub) * 32 + slot * 8];
      bfr[x] = *(const half8*)&Bb[(wn + x * 16 + rsub) * 32 + slot * 8];
    }
#pragma unroll
    for (int mi = 0; mi < 4; ++mi)
#pragma unroll
      for (int ni = 0; ni < 4; ++ni)
        acc[mi][ni] = __builtin_amdgcn_mfma_f32_16x16x32_f16(af[mi], bfr[ni], acc[mi][ni], 0, 0, 0);
  };

  // prologue: stage tile 0 into buf 0; barrier drains it (compiler vmcnt(0))
  stage(0, 0);
  __syncthreads();
  for (int kt = 0; kt < kiters; kt += 2) {
    stage(1, kt + 1);            // overlaps compute(0)
    compute(0);
    __syncthreads();             // buf1 staged + everyone done reading buf0
    if (kt + 2 < kiters) stage(0, kt + 2);  // overlaps compute(1)
    compute(1);
    if (kt + 2 < kiters) __syncthreads();   // buf0 staged + done reading buf1
  }

  const int cn = n0 + wn + rsub;
  const int rm = m0 + wm + j * 4;

  if (OUTMODE == 3) {
    bool ok[4];
#pragma unroll
    for (int ni = 0; ni < 4; ++ni) {
      const int n = cn + ni * 16;
      const int nc = n < nvalid ? n : nvalid - 1;   // clamped (always in-bounds) load
      ok[ni] = (n < nvalid) && (mrow[nc] == 0);
    }
#pragma unroll
    for (int mi = 0; mi < 4; ++mi) {
#pragma unroll
      for (int r = 0; r < 4; ++r) {
        const int m = rm + mi * 16 + r;
        float rowsum = 0.f;
#pragma unroll
        for (int ni = 0; ni < 4; ++ni) {
          const int n = cn + ni * 16;
          const float e = ok[ni] ? __expf(acc[mi][ni][r] * scale) : 0.f;
          ((_Float16*)C)[(size_t)m * ldc + n] = (_Float16)e;
          rowsum += e;
        }
        // reduce over the 16-lane n-group, one atomic per row per group
#pragma unroll
        for (int d = 1; d < 16; d <<= 1) rowsum += __shfl_xor(rowsum, d);
        if (rsub == 0) atomicAdd(&lsum[m], rowsum);
      }
    }
    return;
  }

  if (OUTMODE == 1) {
    // C[n][m]: 4 consecutive m per lane -> packed 8B stores
#pragma unroll
    for (int ni = 0; ni < 4; ++ni) {
      const int n = cn + ni * 16;
      const float bi = bias ? bias[n] : 0.f;
#pragma unroll
      for (int mi = 0; mi < 4; ++mi) {
        half4v pk;
#pragma unroll
        for (int r = 0; r < 4; ++r) pk[r] = (_Float16)(acc[mi][ni][r] * scale + bi);
        *(half4v*)&((_Float16*)C)[(size_t)n * ldc + rm + mi * 16] = pk;
      }
    }
    return;
  }

#pragma unroll
  for (int ni = 0; ni < 4; ++ni) {
    const int n = cn + ni * 16;
    const float bi = (OUTMODE == 0 && bias) ? bias[n] : 0.f;
#pragma unroll
    for (int mi = 0; mi < 4; ++mi) {
#pragma unroll
      for (int r = 0; r < 4; ++r) {
        const int m = rm + mi * 16 + r;
        const float v = acc[mi][ni][r] * scale + bi;
        if (OUTMODE == 0) ((_Float16*)C)[(size_t)m * ldc + n] = (_Float16)v;
        else ((float*)C)[(size_t)m * ldc + n] = v;
      }
    }
  }
}

// ---------------------------------------------------------------- generic batched/split-K GEMM
template <int OUTMODE>
__global__ __launch_bounds__(256) void gemm_nt_kernel(
    const _Float16* __restrict__ Aall, size_t strideA, int lda,
    const _Float16* __restrict__ Btall, size_t strideB, int ldb,
    const float* __restrict__ bias,
    void* __restrict__ Call, size_t strideC, size_t strideS,
    int ldc, int Mvalid, int kiters, int nslices, int sliceK, float scale) {
  __shared__ __align__(16) _Float16 As[8192];
  __shared__ __align__(16) _Float16 Bs[8192];
  // XCD-chunked swizzle of flattened id (grid product % 8 == 0 at all call
  // sites): blocks sharing an A-tile / B-panel land consecutively on one XCD.
  const int nx = gridDim.x, ny = gridDim.y;
  int id = (int)blockIdx.x + nx * ((int)blockIdx.y + ny * (int)blockIdx.z);
  const int tot = nx * ny * (int)gridDim.z;
  id = (id & 7) * (tot >> 3) + (id >> 3);
  const int bx = id % nx;
  const int by = (id / nx) % ny;
  const int bz = id / (nx * ny);
  const int batch = bz / nslices;
  const int slice = bz % nslices;
  const _Float16* A = Aall + (size_t)batch * strideA;
  const _Float16* Bt = Btall + (size_t)batch * strideB;
  char* C = (char*)Call + ((size_t)batch * strideC + (size_t)slice * strideS) *
                          (OUTMODE == 2 ? 4 : 2);
  gemm_tile<OUTMODE>(A, lda, Bt, ldb, bias, (void*)C, ldc, Mvalid,
                     by * 128, bx * 128, slice * sliceK, kiters,
                     scale, As, Bs, nullptr, nullptr, 0);
}

// ---------------------------------------------------------------- scores GEMM + fused exp/mask + row sums
__global__ __launch_bounds__(256) void scores_kernel(
    const _Float16* __restrict__ Qh, const _Float16* __restrict__ Kp,
    _Float16* __restrict__ sc, const unsigned char* __restrict__ mask,
    float* __restrict__ lsum) {
  __shared__ __align__(16) _Float16 As[8192];
  __shared__ __align__(16) _Float16 Bs[8192];
  const int nx = gridDim.x, ny = gridDim.y;  // (12, 16, 4)
  int id = (int)blockIdx.x + nx * ((int)blockIdx.y + ny * (int)blockIdx.z);
  const int tot = nx * ny * (int)gridDim.z;  // 768
  id = (id & 7) * (tot >> 3) + (id >> 3);
  const int bx = id % nx;
  const int by = (id / nx) % ny;
  const int b = id / (nx * ny);
  gemm_tile<3>(Qh + (size_t)b * LQ_ * A_, A_, Kp + (size_t)b * TMP_ * A_, A_, nullptr,
               (void*)(sc + (size_t)b * LQ_ * TMP_), TMP_, LQ_,
               by * 128, bx * 128, 0, 16, 0.044194173824159216f,
               As, Bs, mask + (size_t)b * TM_, lsum + (size_t)b * LQ_, TM_);
}

// ---------------------------------------------------------------- fused Q + K + V projections
// blocks 0..511: Q split-K (ks), 512..703: K, 704..895: V(transposed out)
// Each section gets an XCD-chunked bijective remap (section sizes 512/192/192,
// section bases 512/704 are multiples of 8, so bid0%8 still selects the XCD).
__global__ __launch_bounds__(256) void qkv_kernel(
    const _Float16* __restrict__ hnorm, const _Float16* __restrict__ WqT,
    float* __restrict__ Qpart,
    const _Float16* __restrict__ memh, const _Float16* __restrict__ WkT,
    const float* __restrict__ bk, _Float16* __restrict__ Kp,
    const _Float16* __restrict__ WvT, const float* __restrict__ bv,
    _Float16* __restrict__ VT) {
  __shared__ __align__(16) _Float16 As[8192];
  __shared__ __align__(16) _Float16 Bs[8192];
  const int bid0 = blockIdx.x;
  if (bid0 < 512) {
    const int bid = ((bid0 & 7) << 6) | (bid0 >> 3);  // chunked: 64 blocks/XCD
    const int nb = bid & 3, mb = (bid >> 2) & 63, ks = bid >> 8;
    gemm_tile<2>(hnorm, H_, WqT, H_, nullptr,
                 (void*)(Qpart + (size_t)ks * 8192 * A_), A_,
                 8192, mb * 128, nb * 128, ks * 2048, 64, 1.f, As, Bs,
                 nullptr, nullptr, 0);
  } else if (bid0 < 704) {
    int t = bid0 - 512;
    t = (t & 7) * 24 + (t >> 3);                      // chunked: 24 blocks/XCD
    const int nb = t & 3, mb = (t >> 2) % 12, b = t / 48;
    gemm_tile<0>(memh + (size_t)b * TM_ * D_, D_, WkT, D_, bk,
                 (void*)(Kp + (size_t)b * TMP_ * A_), A_,
                 TM_, mb * 128, nb * 128, 0, 32, 1.f, As, Bs,
                 nullptr, nullptr, 0);
  } else {
    int t = bid0 - 704;
    t = (t & 7) * 24 + (t >> 3);
    const int nb = t & 3, mb = (t >> 2) % 12, b = t / 48;
    gemm_tile<1>(memh + (size_t)b * TM_ * D_, D_, WvT, D_, bv,
                 (void*)(VT + (size_t)b * A_ * TMP_), TMP_,
                 TM_, mb * 128, nb * 128, 0, 32, 1.f, As, Bs,
                 nullptr, nullptr, 0);
  }
}

// ---------------------------------------------------------------- split-K reduces
// blocks >= 4096 zero the lsum buffer (8192 floats) for the scores pass
__global__ __launch_bounds__(256) void qreduce_kernel(
    const float* __restrict__ p, const float* __restrict__ bias,
    _Float16* __restrict__ out, float* __restrict__ lsum) {
  const int bid = blockIdx.x;
  if (bid >= 4096) {
    lsum[(bid - 4096) * 256 + threadIdx.x] = 0.f;
    return;
  }
  const size_t i = ((size_t)bid * 256 + threadIdx.x) * 4;  // 8192*512 total
  const float4 a = *(const float4*)(p + i);
  const float4 b = *(const float4*)(p + (size_t)8192 * A_ + i);
  const float4 bi = *(const float4*)(bias + (i & (A_ - 1)));
  half4v o;
  o.x = (_Float16)(a.x + b.x + bi.x);
  o.y = (_Float16)(a.y + b.y + bi.y);
  o.z = (_Float16)(a.z + b.z + bi.z);
  o.w = (_Float16)(a.w + b.w + bi.w);
  *(half4v*)(out + i) = o;
}

__global__ __launch_bounds__(256) void areduce_kernel(
    const float* __restrict__ p, const float* __restrict__ lsum,
    _Float16* __restrict__ out) {
  const size_t S = (size_t)B_ * LQ_ * A_;
  const size_t i = ((size_t)blockIdx.x * 256 + threadIdx.x) * 4;
  const float4 a = *(const float4*)(p + i);
  const float4 b = *(const float4*)(p + S + i);
  const float4 c = *(const float4*)(p + 2 * S + i);
  const float inv = 1.f / lsum[i >> 9];  // row = i / 512; all 4 elems same row
  half4v o;
  o.x = (_Float16)((a.x + b.x + c.x) * inv);
  o.y = (_Float16)((a.y + b.y + c.y) * inv);
  o.z = (_Float16)((a.z + b.z + c.z) * inv);
  o.w = (_Float16)((a.w + b.w + c.w) * inv);
  *(half4v*)(out + i) = o;
}

// ---------------------------------------------------------------- fused prep:
// blocks [0,8192): LN1 rows; [8192,9692): mem fp32->f16; rest: 4 weight transposes
__global__ __launch_bounds__(256) void prep_kernel(
    const float* __restrict__ hidden, const float* __restrict__ lnw,
    const float* __restrict__ lnb, _Float16* __restrict__ hnorm,
    const float* __restrict__ mem, _Float16* __restrict__ memh,
    const float* __restrict__ Wq, _Float16* __restrict__ WqT,
    const float* __restrict__ Wk, _Float16* __restrict__ WkT,
    const float* __restrict__ Wv, _Float16* __restrict__ WvT,
    const float* __restrict__ Wo, _Float16* __restrict__ WoT) {
  __shared__ float smem[32 * 33];
  int bid = blockIdx.x;
  const int t = threadIdx.x;
  if (bid < 8192) {  // ---- LN1 row
    const float* x = hidden + (size_t)bid * H_;
    _Float16* y = hnorm + (size_t)bid * H_;
    float4 v[4];
    float s = 0.f, ss = 0.f;
#pragma unroll
    for (int i = 0; i < 4; ++i) {
      v[i] = ((const float4*)x)[t + 256 * i];
      s  += v[i].x + v[i].y + v[i].z + v[i].w;
      ss += v[i].x * v[i].x + v[i].y * v[i].y + v[i].z * v[i].z + v[i].w * v[i].w;
    }
    const int lane = t & 63, wv = t >> 6;
#pragma unroll
    for (int off = 32; off; off >>= 1) { s += __shfl_down(s, off); ss += __shfl_down(ss, off); }
    if (lane == 0) { smem[wv] = s; smem[4 + wv] = ss; }
    __syncthreads();
    s  = smem[0] + smem[1] + smem[2] + smem[3];
    ss = smem[4] + smem[5] + smem[6] + smem[7];
    const float mu = s * (1.f / H_);
    const float var = ss * (1.f / H_) - mu * mu;
    const float rstd = rsqrtf(var + EPS_);
#pragma unroll
    for (int i = 0; i < 4; ++i) {
      float4 wv4 = ((const float4*)lnw)[t + 256 * i];
      float4 bv4 = ((const float4*)lnb)[t + 256 * i];
      half4v o;
      o.x = (_Float16)((v[i].x - mu) * rstd * wv4.x + bv4.x);
      o.y = (_Float16)((v[i].y - mu) * rstd * wv4.y + bv4.y);
      o.z = (_Float16)((v[i].z - mu) * rstd * wv4.z + bv4.z);
      o.w = (_Float16)((v[i].w - mu) * rstd * wv4.w + bv4.w);
      ((half4v*)y)[t + 256 * i] = o;
    }
    return;
  }
  bid -= 8192;
  if (bid < 1500) {  // ---- mem fp32 -> f16
    const size_t i = ((size_t)bid * 256 + t) * 4;
    float4 f = *(const float4*)(mem + i);
    half4v o;
    o.x = (_Float16)f.x; o.y = (_Float16)f.y; o.z = (_Float16)f.z; o.w = (_Float16)f.w;
    *(half4v*)(memh + i) = o;
    return;
  }
  bid -= 1500;
  // ---- weight transpose fp32 [R][C] -> f16 [C][R]
  const float* src;
  _Float16* dst;
  int R, C;
  if (bid < 2048) { src = Wq; dst = WqT; R = 4096; C = 512; }
  else if (bid < 2048 + 512) { bid -= 2048; src = Wk; dst = WkT; R = 1024; C = 512; }
  else if (bid < 2048 + 1024) { bid -= 2048 + 512; src = Wv; dst = WvT; R = 1024; C = 512; }
  else { bid -= 2048 + 1024; src = Wo; dst = WoT; R = 512; C = 4096; }
  const int nbx = C / 32;
  const int bx = bid % nbx, by = bid / nbx;
  const int tx = t & 31, ty = t >> 5;
  const int c0 = bx * 32, r0 = by * 32;
#pragma unroll
  for (int i = 0; i < 32; i += 8)
    smem[(ty + i) * 33 + tx] = src[(size_t)(r0 + ty + i) * C + c0 + tx];
  __syncthreads();
#pragma unroll
  for (int i = 0; i < 32; i += 8)
    dst[(size_t)(c0 + ty + i) * R + r0 + tx] = (_Float16)smem[tx * 33 + ty + i];
}

// ---------------------------------------------------------------- LN2 + gate epilogue -> out (fp32)
__global__ __launch_bounds__(256) void ln2_gate_kernel(
    const float* __restrict__ hidden_, const _Float16* __restrict__ ctxh_,
    const float* __restrict__ w, const float* __restrict__ bvec,
    const float* __restrict__ gate_logit, float* __restrict__ out_) {
  const int row = blockIdx.x;
  const float* h = hidden_ + (size_t)row * H_;
  const _Float16* c = ctxh_ + (size_t)row * H_;
  float* o = out_ + (size_t)row * H_;
  const int t = threadIdx.x;
  float4 hv[4];
  float xv[16];
  float s = 0.f, ss = 0.f;
#pragma unroll
  for (int i = 0; i < 4; ++i) {
    hv[i] = ((const float4*)h)[t + 256 * i];
    half4v cv = ((const half4v*)c)[t + 256 * i];
    xv[4 * i + 0] = hv[i].x + (float)cv.x;
    xv[4 * i + 1] = hv[i].y + (float)cv.y;
    xv[4 * i + 2] = hv[i].z + (float)cv.z;
    xv[4 * i + 3] = hv[i].w + (float)cv.w;
    s  += xv[4 * i + 0] + xv[4 * i + 1] + xv[4 * i + 2] + xv[4 * i + 3];
    ss += xv[4 * i + 0] * xv[4 * i + 0] + xv[4 * i + 1] * xv[4 * i + 1] +
          xv[4 * i + 2] * xv[4 * i + 2] + xv[4 * i + 3] * xv[4 * i + 3];
  }
  __shared__ float red[2][4];
  const int lane = t & 63, wv = t >> 6;
#pragma unroll
  for (int off = 32; off; off >>= 1) { s += __shfl_down(s, off); ss += __shfl_down(ss, off); }
  if (lane == 0) { red[0][wv] = s; red[1][wv] = ss; }
  __syncthreads();
  s  = red[0][0] + red[0][1] + red[0][2] + red[0][3];
  ss = red[1][0] + red[1][1] + red[1][2] + red[1][3];
  const float mu = s * (1.f / H_);
  const float var = ss * (1.f / H_) - mu * mu;
  const float rstd = rsqrtf(var + EPS_);
  const float g = 1.f / (1.f + __expf(-gate_logit[0]));
#pragma unroll
  for (int i = 0; i < 4; ++i) {
    float4 wv4 = ((const float4*)w)[t + 256 * i];
    float4 bv4 = ((const float4*)bvec)[t + 256 * i];
    float4 ov;
    ov.x = hv[i].x + g * ((xv[4 * i + 0] - mu) * rstd * wv4.x + bv4.x - hv[i].x);
    ov.y = hv[i].y + g * ((xv[4 * i + 1] - mu) * rstd * wv4.y + bv4.y - hv[i].y);
    ov.z = hv[i].z + g * ((xv[4 * i + 2] - mu) * rstd * wv4.z + bv4.z - hv[i].z);
    ov.w = hv[i].w + g * ((xv[4 * i + 3] - mu) * rstd * wv4.w + bv4.w - hv[i].w);
    ((float4*)o)[t + 256 * i] = ov;
  }
}

// ---------------------------------------------------------------- launcher
extern "C" void kernel_launch(void* const* d_in, const int* in_sizes, int n_in,
                              void* d_out, int out_size, void* d_ws, size_t ws_size,
                              hipStream_t stream) {
  const float* hidden = (const float*)d_in[0];
  const float* mem    = (const float*)d_in[1];
  const unsigned char* mask = (const unsigned char*)d_in[2];
  const float* Wq = (const float*)d_in[3];
  const float* bq = (const float*)d_in[4];
  const float* Wk = (const float*)d_in[5];
  const float* bk = (const float*)d_in[6];
  const float* Wv = (const float*)d_in[7];
  const float* bv = (const float*)d_in[8];
  const float* Wo = (const float*)d_in[9];
  const float* bo = (const float*)d_in[10];
  const float* lnw1 = (const float*)d_in[11];
  const float* lnb1 = (const float*)d_in[12];
  const float* lnw2 = (const float*)d_in[13];
  const float* lnb2 = (const float*)d_in[14];
  const float* gate = (const float*)d_in[15];
  float* out = (float*)d_out;

  // workspace layout (f16 elements)
  _Float16* p = (_Float16*)d_ws;
  _Float16* hnorm = p; p += (size_t)8192 * H_;        // 67.1 MB; later: attn fp32 partials (50.3 MB), then ctx_h
  _Float16* Qh    = p; p += (size_t)8192 * A_;        // 8.4 MB
  _Float16* memh  = p; p += (size_t)6000 * D_;        // 12.3 MB
  _Float16* WqT   = p; p += (size_t)A_ * H_;          // [A][H]
  _Float16* WkT   = p; p += (size_t)A_ * D_;          // [A][D] (dead after qkv -> lsum alias)
  _Float16* WvT   = p; p += (size_t)A_ * D_;
  _Float16* WoT   = p; p += (size_t)H_ * A_;          // [H][A]
  _Float16* Kp    = p; p += (size_t)B_ * TMP_ * A_;   // [B][1536][512]
  _Float16* VT    = p; p += (size_t)B_ * A_ * TMP_;   // [B][512][1536]
  _Float16* sc    = p; p += (size_t)B_ * LQ_ * TMP_;  // [B][2048][1536] exp-scores
  _Float16* ctx   = p; p += (size_t)8192 * A_;        // [8192][512]
  // aliases (disjoint lifetimes):
  float* Qpart = (float*)sc;      // 2 x 8192 x 512 fp32 = 33.55 MB == sizeof(sc)+sizeof(ctx)
  float* Apart = (float*)hnorm;   // 3 x 4 x 2048 x 512 fp32 = 50.3 MB <= 67.1 MB
  float* lsum  = (float*)WkT;     // 8192 fp32 = 32 KB; WkT dead after qkv; zeroed in qreduce

  // 1. prep: LN1 + mem->f16 + 4 weight transposes (one dispatch)
  prep_kernel<<<8192 + 1500 + 2048 + 512 + 512 + 2048, 256, 0, stream>>>(
      hidden, lnw1, lnb1, hnorm, mem, memh, Wq, WqT, Wk, WkT, Wv, WvT, Wo, WoT);
  // 2. fused Q(split-K x2) + K + V projections: 896 blocks (~3.5/CU)
  qkv_kernel<<<896, 256, 0, stream>>>(hnorm, WqT, Qpart, memh, WkT, bk, Kp, WvT, bv, VT);
  // 3. Q = sum partials + bq -> f16; tail blocks zero lsum
  qreduce_kernel<<<4096 + 32, 256, 0, stream>>>(Qpart, bq, Qh, lsum);
  // 4. exp-scores = exp(Q @ K^T / sqrt(A)) with mask/pad zeroing + row sums
  scores_kernel<<<dim3(12, 16, 4), 256, 0, stream>>>(Qh, Kp, sc, mask, lsum);
  // 5. ctx partials = exp-scores @ V, split-K x3 (K=512 each): 768 blocks
  gemm_nt_kernel<2><<<dim3(4, 16, 12), 256, 0, stream>>>(
      sc, (size_t)LQ_ * TMP_, TMP_, VT, (size_t)A_ * TMP_, TMP_, nullptr,
      (void*)Apart, (size_t)LQ_ * A_, (size_t)B_ * LQ_ * A_, A_, LQ_, 16, 3, 512, 1.f);
  // 6. ctx = (sum partials) / lsum -> f16
  areduce_kernel<<<4096, 256, 0, stream>>>(Apart, lsum, ctx);
  // 7. ctx_h = ctx @ Wo + bo -> reuse hnorm buffer  [8192][4096] (2048 blocks)
  gemm_nt_kernel<0><<<dim3(32, 64, 1), 256, 0, stream>>>(
      ctx, 0, A_, WoT, 0, A_, bo, (void*)hnorm, 0, 0, H_, 8192, 16, 1, 0, 1.f);
  // 8. out = hidden + g*(LN(hidden+ctx_h) - hidden)
  ln2_gate_kernel<<<8192, 256, 0, stream>>>(hidden, hnorm, lnw2, lnb2, gate, out);
}

// Round 2
// 507.720 us; speedup vs baseline: 1.0578x; 1.0578x over previous
//
#include <hip/hip_runtime.h>
#include <cstdint>
#include <cstddef>

// Problem constants
#define H_   4096
#define D_   1024
#define A_   512
#define B_   4
#define LQ_  2048
#define TM_  1500
#define TMP_ 1536   // TM padded to multiple of 128
#define EPS_ 1e-5f

typedef __attribute__((ext_vector_type(8))) _Float16 half8;
typedef __attribute__((ext_vector_type(4))) _Float16 half4v;
typedef __attribute__((ext_vector_type(4))) float f32x4;

// ---------------------------------------------------------------- helpers
__device__ __forceinline__ void gload_lds16(void* g, void* l) {
  // async global->LDS, 16B per lane; LDS dest = wave-uniform base + lane*16
  __builtin_amdgcn_global_load_lds((__attribute__((address_space(1))) void*)g,
                                   (__attribute__((address_space(3))) void*)l,
                                   16, 0, 0);
}

// ---------------------------------------------------------------- core 128x128 MFMA tile
// C[m][n] = scale * sum_k A[m][k] * Bt[n][k] (+ bias[n])
// OUTMODE: 0 = f16 row-major, 1 = f16 transposed (C[n][m], packed 8B stores),
//          2 = fp32 row-major (no bias), 3 = exp-scores: write f16 exp(v*scale)
//              with mask/pad zeroing + per-row atomic sums into lsum.
// LDS chunk swizzle: global 16B chunk (cs ^ ((r>>1)&3)) lands in LDS slot cs ->
// reader slot j^((rsub>>1)&3); 0 bank conflicts measured (R2).
// R2 post-mortem: explicit LDS double-buffering (R1) cut occupancy 26%->18.5%
// and REGRESSED (m99/m100 precedent) -- single-buffered 16KB loop restored;
// implicit wave-level TLP covers the staging latency, and with the XCD swizzle
// (kept from R1, FETCH 191->55MB) the pre-barrier drain now fills from L2.
template <int OUTMODE>
__device__ __forceinline__ void gemm_tile(
    const _Float16* __restrict__ A, int lda,
    const _Float16* __restrict__ Bt, int ldb,
    const float* __restrict__ bias,
    void* __restrict__ C, int ldc,
    int Mvalid, int m0, int n0, int kbase, int kiters, float scale,
    _Float16* As, _Float16* Bs,
    const unsigned char* __restrict__ mrow, float* __restrict__ lsum, int nvalid) {
  const int tid = threadIdx.x;
  const int lane = tid & 63;
  const int wave = tid >> 6;

  f32x4 acc[4][4];
#pragma unroll
  for (int i = 0; i < 4; ++i)
#pragma unroll
    for (int jj = 0; jj < 4; ++jj) acc[i][jj] = (f32x4){0.f, 0.f, 0.f, 0.f};

  // staging: 128x32 f16 tile = 512 chunks of 16B; 256 threads x 2 chunks each
  const _Float16* gA[2];
  const _Float16* gB[2];
  _Float16* lA[2];
  _Float16* lB[2];
#pragma unroll
  for (int i = 0; i < 2; ++i) {
    const int c = wave * 64 + lane + 256 * i;
    const int r = c >> 2;
    const int cs = c & 3;
    const int col = (cs ^ ((r >> 1) & 3)) * 8;  // XOR-swizzled 16B chunk
    int ra = m0 + r;
    if (ra >= Mvalid) ra = Mvalid - 1;  // clamp (pad rows dup last valid row)
    gA[i] = A + (size_t)ra * lda + kbase + col;
    gB[i] = Bt + (size_t)(n0 + r) * ldb + kbase + col;
    lA[i] = As + wave * 512 + i * 2048;  // wave-uniform LDS base (linear layout)
    lB[i] = Bs + wave * 512 + i * 2048;
  }

  const int wm = (wave >> 1) * 64;
  const int wn = (wave & 1) * 64;
  const int rsub = lane & 15;
  const int j = lane >> 4;                 // which 16B chunk of the 32-wide K row
  const int slot = j ^ ((rsub >> 1) & 3);  // swizzled LDS slot (constant per lane)

  for (int kt = 0; kt < kiters; ++kt) {
    const int ko = kt * 32;
#pragma unroll
    for (int i = 0; i < 2; ++i) {
      gload_lds16((void*)(gA[i] + ko), (void*)lA[i]);
      gload_lds16((void*)(gB[i] + ko), (void*)lB[i]);
    }
    __syncthreads();
    half8 af[4], bfr[4];
#pragma unroll
    for (int x = 0; x < 4; ++x) {
      af[x]  = *(const half8*)&As[(wm + x * 16 + rsub) * 32 + slot * 8];
      bfr[x] = *(const half8*)&Bs[(wn + x * 16 + rsub) * 32 + slot * 8];
    }
#pragma unroll
    for (int mi = 0; mi < 4; ++mi)
#pragma unroll
      for (int ni = 0; ni < 4; ++ni)
        acc[mi][ni] = __builtin_amdgcn_mfma_f32_16x16x32_f16(af[mi], bfr[ni], acc[mi][ni], 0, 0, 0);
    __syncthreads();
  }

  const int cn = n0 + wn + rsub;
  const int rm = m0 + wm + j * 4;

  if (OUTMODE == 3) {
    bool ok[4];
#pragma unroll
    for (int ni = 0; ni < 4; ++ni) {
      const int n = cn + ni * 16;
      const int nc = n < nvalid ? n : nvalid - 1;   // clamped (always in-bounds) load
      ok[ni] = (n < nvalid) && (mrow[nc] == 0);
    }
#pragma unroll
    for (int mi = 0; mi < 4; ++mi) {
#pragma unroll
      for (int r = 0; r < 4; ++r) {
        const int m = rm + mi * 16 + r;
        float rowsum = 0.f;
#pragma unroll
        for (int ni = 0; ni < 4; ++ni) {
          const int n = cn + ni * 16;
          const float e = ok[ni] ? __expf(acc[mi][ni][r] * scale) : 0.f;
          ((_Float16*)C)[(size_t)m * ldc + n] = (_Float16)e;
          rowsum += e;
        }
        // reduce over the 16-lane n-group, one atomic per row per group
#pragma unroll
        for (int d = 1; d < 16; d <<= 1) rowsum += __shfl_xor(rowsum, d);
        if (rsub == 0) atomicAdd(&lsum[m], rowsum);
      }
    }
    return;
  }

  if (OUTMODE == 1) {
    // C[n][m]: 4 consecutive m per lane -> packed 8B stores
#pragma unroll
    for (int ni = 0; ni < 4; ++ni) {
      const int n = cn + ni * 16;
      const float bi = bias ? bias[n] : 0.f;
#pragma unroll
      for (int mi = 0; mi < 4; ++mi) {
        half4v pk;
#pragma unroll
        for (int r = 0; r < 4; ++r) pk[r] = (_Float16)(acc[mi][ni][r] * scale + bi);
        *(half4v*)&((_Float16*)C)[(size_t)n * ldc + rm + mi * 16] = pk;
      }
    }
    return;
  }

#pragma unroll
  for (int ni = 0; ni < 4; ++ni) {
    const int n = cn + ni * 16;
    const float bi = (OUTMODE == 0 && bias) ? bias[n] : 0.f;
#pragma unroll
    for (int mi = 0; mi < 4; ++mi) {
#pragma unroll
      for (int r = 0; r < 4; ++r) {
        const int m = rm + mi * 16 + r;
        const float v = acc[mi][ni][r] * scale + bi;
        if (OUTMODE == 0) ((_Float16*)C)[(size_t)m * ldc + n] = (_Float16)v;
        else ((float*)C)[(size_t)m * ldc + n] = v;
      }
    }
  }
}

// ---------------------------------------------------------------- generic batched/split-K GEMM
template <int OUTMODE>
__global__ __launch_bounds__(256) void gemm_nt_kernel(
    const _Float16* __restrict__ Aall, size_t strideA, int lda,
    const _Float16* __restrict__ Btall, size_t strideB, int ldb,
    const float* __restrict__ bias,
    void* __restrict__ Call, size_t strideC, size_t strideS,
    int ldc, int Mvalid, int kiters, int nslices, int sliceK, float scale) {
  __shared__ __align__(16) _Float16 As[4096];
  __shared__ __align__(16) _Float16 Bs[4096];
  // XCD-chunked swizzle of flattened id (grid product % 8 == 0 at all call
  // sites): blocks sharing an A-tile / B-panel land consecutively on one XCD.
  // R1 measured: FETCH_SIZE 191MB -> 55MB on qkv. Keeper.
  const int nx = gridDim.x, ny = gridDim.y;
  int id = (int)blockIdx.x + nx * ((int)blockIdx.y + ny * (int)blockIdx.z);
  const int tot = nx * ny * (int)gridDim.z;
  id = (id & 7) * (tot >> 3) + (id >> 3);
  const int bx = id % nx;
  const int by = (id / nx) % ny;
  const int bz = id / (nx * ny);
  const int batch = bz / nslices;
  const int slice = bz % nslices;
  const _Float16* A = Aall + (size_t)batch * strideA;
  const _Float16* Bt = Btall + (size_t)batch * strideB;
  char* C = (char*)Call + ((size_t)batch * strideC + (size_t)slice * strideS) *
                          (OUTMODE == 2 ? 4 : 2);
  gemm_tile<OUTMODE>(A, lda, Bt, ldb, bias, (void*)C, ldc, Mvalid,
                     by * 128, bx * 128, slice * sliceK, kiters,
                     scale, As, Bs, nullptr, nullptr, 0);
}

// ---------------------------------------------------------------- scores GEMM + fused exp/mask + row sums
__global__ __launch_bounds__(256) void scores_kernel(
    const _Float16* __restrict__ Qh, const _Float16* __restrict__ Kp,
    _Float16* __restrict__ sc, const unsigned char* __restrict__ mask,
    float* __restrict__ lsum) {
  __shared__ __align__(16) _Float16 As[4096];
  __shared__ __align__(16) _Float16 Bs[4096];
  const int nx = gridDim.x, ny = gridDim.y;  // (12, 16, 4)
  int id = (int)blockIdx.x + nx * ((int)blockIdx.y + ny * (int)blockIdx.z);
  const int tot = nx * ny * (int)gridDim.z;  // 768
  id = (id & 7) * (tot >> 3) + (id >> 3);
  const int bx = id % nx;
  const int by = (id / nx) % ny;
  const int b = id / (nx * ny);
  gemm_tile<3>(Qh + (size_t)b * LQ_ * A_, A_, Kp + (size_t)b * TMP_ * A_, A_, nullptr,
               (void*)(sc + (size_t)b * LQ_ * TMP_), TMP_, LQ_,
               by * 128, bx * 128, 0, 16, 0.044194173824159216f,
               As, Bs, mask + (size_t)b * TM_, lsum + (size_t)b * LQ_, TM_);
}

// ---------------------------------------------------------------- fused Q + K + V projections
// blocks 0..511: Q split-K (ks), 512..703: K, 704..895: V(transposed out)
// Each section gets an XCD-chunked bijective remap (section sizes 512/192/192,
// section bases 512/704 are multiples of 8, so bid0%8 still selects the XCD).
__global__ __launch_bounds__(256) void qkv_kernel(
    const _Float16* __restrict__ hnorm, const _Float16* __restrict__ WqT,
    float* __restrict__ Qpart,
    const _Float16* __restrict__ memh, const _Float16* __restrict__ WkT,
    const float* __restrict__ bk, _Float16* __restrict__ Kp,
    const _Float16* __restrict__ WvT, const float* __restrict__ bv,
    _Float16* __restrict__ VT) {
  __shared__ __align__(16) _Float16 As[4096];
  __shared__ __align__(16) _Float16 Bs[4096];
  const int bid0 = blockIdx.x;
  if (bid0 < 512) {
    const int bid = ((bid0 & 7) << 6) | (bid0 >> 3);  // chunked: 64 blocks/XCD
    const int nb = bid & 3, mb = (bid >> 2) & 63, ks = bid >> 8;
    gemm_tile<2>(hnorm, H_, WqT, H_, nullptr,
                 (void*)(Qpart + (size_t)ks * 8192 * A_), A_,
                 8192, mb * 128, nb * 128, ks * 2048, 64, 1.f, As, Bs,
                 nullptr, nullptr, 0);
  } else if (bid0 < 704) {
    int t = bid0 - 512;
    t = (t & 7) * 24 + (t >> 3);                      // chunked: 24 blocks/XCD
    const int nb = t & 3, mb = (t >> 2) % 12, b = t / 48;
    gemm_tile<0>(memh + (size_t)b * TM_ * D_, D_, WkT, D_, bk,
                 (void*)(Kp + (size_t)b * TMP_ * A_), A_,
                 TM_, mb * 128, nb * 128, 0, 32, 1.f, As, Bs,
                 nullptr, nullptr, 0);
  } else {
    int t = bid0 - 704;
    t = (t & 7) * 24 + (t >> 3);
    const int nb = t & 3, mb = (t >> 2) % 12, b = t / 48;
    gemm_tile<1>(memh + (size_t)b * TM_ * D_, D_, WvT, D_, bv,
                 (void*)(VT + (size_t)b * A_ * TMP_), TMP_,
                 TM_, mb * 128, nb * 128, 0, 32, 1.f, As, Bs,
                 nullptr, nullptr, 0);
  }
}

// ---------------------------------------------------------------- split-K reduces
// blocks >= 4096 zero the lsum buffer (8192 floats) for the scores pass
__global__ __launch_bounds__(256) void qreduce_kernel(
    const float* __restrict__ p, const float* __restrict__ bias,
    _Float16* __restrict__ out, float* __restrict__ lsum) {
  const int bid = blockIdx.x;
  if (bid >= 4096) {
    lsum[(bid - 4096) * 256 + threadIdx.x] = 0.f;
    return;
  }
  const size_t i = ((size_t)bid * 256 + threadIdx.x) * 4;  // 8192*512 total
  const float4 a = *(const float4*)(p + i);
  const float4 b = *(const float4*)(p + (size_t)8192 * A_ + i);
  const float4 bi = *(const float4*)(bias + (i & (A_ - 1)));
  half4v o;
  o.x = (_Float16)(a.x + b.x + bi.x);
  o.y = (_Float16)(a.y + b.y + bi.y);
  o.z = (_Float16)(a.z + b.z + bi.z);
  o.w = (_Float16)(a.w + b.w + bi.w);
  *(half4v*)(out + i) = o;
}

__global__ __launch_bounds__(256) void areduce_kernel(
    const float* __restrict__ p, const float* __restrict__ lsum,
    _Float16* __restrict__ out) {
  const size_t S = (size_t)B_ * LQ_ * A_;
  const size_t i = ((size_t)blockIdx.x * 256 + threadIdx.x) * 4;
  const float4 a = *(const float4*)(p + i);
  const float4 b = *(const float4*)(p + S + i);
  const float4 c = *(const float4*)(p + 2 * S + i);
  const float inv = 1.f / lsum[i >> 9];  // row = i / 512; all 4 elems same row
  half4v o;
  o.x = (_Float16)((a.x + b.x + c.x) * inv);
  o.y = (_Float16)((a.y + b.y + c.y) * inv);
  o.z = (_Float16)((a.z + b.z + c.z) * inv);
  o.w = (_Float16)((a.w + b.w + c.w) * inv);
  *(half4v*)(out + i) = o;
}

// ---------------------------------------------------------------- fused prep:
// blocks [0,8192): LN1 rows; [8192,9692): mem fp32->f16; rest: 4 weight transposes
__global__ __launch_bounds__(256) void prep_kernel(
    const float* __restrict__ hidden, const float* __restrict__ lnw,
    const float* __restrict__ lnb, _Float16* __restrict__ hnorm,
    const float* __restrict__ mem, _Float16* __restrict__ memh,
    const float* __restrict__ Wq, _Float16* __restrict__ WqT,
    const float* __restrict__ Wk, _Float16* __restrict__ WkT,
    const float* __restrict__ Wv, _Float16* __restrict__ WvT,
    const float* __restrict__ Wo, _Float16* __restrict__ WoT) {
  __shared__ float smem[32 * 33];
  int bid = blockIdx.x;
  const int t = threadIdx.x;
  if (bid < 8192) {  // ---- LN1 row
    const float* x = hidden + (size_t)bid * H_;
    _Float16* y = hnorm + (size_t)bid * H_;
    float4 v[4];
    float s = 0.f, ss = 0.f;
#pragma unroll
    for (int i = 0; i < 4; ++i) {
      v[i] = ((const float4*)x)[t + 256 * i];
      s  += v[i].x + v[i].y + v[i].z + v[i].w;
      ss += v[i].x * v[i].x + v[i].y * v[i].y + v[i].z * v[i].z + v[i].w * v[i].w;
    }
    const int lane = t & 63, wv = t >> 6;
#pragma unroll
    for (int off = 32; off; off >>= 1) { s += __shfl_down(s, off); ss += __shfl_down(ss, off); }
    if (lane == 0) { smem[wv] = s; smem[4 + wv] = ss; }
    __syncthreads();
    s  = smem[0] + smem[1] + smem[2] + smem[3];
    ss = smem[4] + smem[5] + smem[6] + smem[7];
    const float mu = s * (1.f / H_);
    const float var = ss * (1.f / H_) - mu * mu;
    const float rstd = rsqrtf(var + EPS_);
#pragma unroll
    for (int i = 0; i < 4; ++i) {
      float4 wv4 = ((const float4*)lnw)[t + 256 * i];
      float4 bv4 = ((const float4*)lnb)[t + 256 * i];
      half4v o;
      o.x = (_Float16)((v[i].x - mu) * rstd * wv4.x + bv4.x);
      o.y = (_Float16)((v[i].y - mu) * rstd * wv4.y + bv4.y);
      o.z = (_Float16)((v[i].z - mu) * rstd * wv4.z + bv4.z);
      o.w = (_Float16)((v[i].w - mu) * rstd * wv4.w + bv4.w);
      ((half4v*)y)[t + 256 * i] = o;
    }
    return;
  }
  bid -= 8192;
  if (bid < 1500) {  // ---- mem fp32 -> f16
    const size_t i = ((size_t)bid * 256 + t) * 4;
    float4 f = *(const float4*)(mem + i);
    half4v o;
    o.x = (_Float16)f.x; o.y = (_Float16)f.y; o.z = (_Float16)f.z; o.w = (_Float16)f.w;
    *(half4v*)(memh + i) = o;
    return;
  }
  bid -= 1500;
  // ---- weight transpose fp32 [R][C] -> f16 [C][R]
  const float* src;
  _Float16* dst;
  int R, C;
  if (bid < 2048) { src = Wq; dst = WqT; R = 4096; C = 512; }
  else if (bid < 2048 + 512) { bid -= 2048; src = Wk; dst = WkT; R = 1024; C = 512; }
  else if (bid < 2048 + 1024) { bid -= 2048 + 512; src = Wv; dst = WvT; R = 1024; C = 512; }
  else { bid -= 2048 + 1024; src = Wo; dst = WoT; R = 512; C = 4096; }
  const int nbx = C / 32;
  const int bx = bid % nbx, by = bid / nbx;
  const int tx = t & 31, ty = t >> 5;
  const int c0 = bx * 32, r0 = by * 32;
#pragma unroll
  for (int i = 0; i < 32; i += 8)
    smem[(ty + i) * 33 + tx] = src[(size_t)(r0 + ty + i) * C + c0 + tx];
  __syncthreads();
#pragma unroll
  for (int i = 0; i < 32; i += 8)
    dst[(size_t)(c0 + ty + i) * R + r0 + tx] = (_Float16)smem[tx * 33 + ty + i];
}

// ---------------------------------------------------------------- LN2 + gate epilogue -> out (fp32)
__global__ __launch_bounds__(256) void ln2_gate_kernel(
    const float* __restrict__ hidden_, const _Float16* __restrict__ ctxh_,
    const float* __restrict__ w, const float* __restrict__ bvec,
    const float* __restrict__ gate_logit, float* __restrict__ out_) {
  const int row = blockIdx.x;
  const float* h = hidden_ + (size_t)row * H_;
  const _Float16* c = ctxh_ + (size_t)row * H_;
  float* o = out_ + (size_t)row * H_;
  const int t = threadIdx.x;
  float4 hv[4];
  float xv[16];
  float s = 0.f, ss = 0.f;
#pragma unroll
  for (int i = 0; i < 4; ++i) {
    hv[i] = ((const float4*)h)[t + 256 * i];
    half4v cv = ((const half4v*)c)[t + 256 * i];
    xv[4 * i + 0] = hv[i].x + (float)cv.x;
    xv[4 * i + 1] = hv[i].y + (float)cv.y;
    xv[4 * i + 2] = hv[i].z + (float)cv.z;
    xv[4 * i + 3] = hv[i].w + (float)cv.w;
    s  += xv[4 * i + 0] + xv[4 * i + 1] + xv[4 * i + 2] + xv[4 * i + 3];
    ss += xv[4 * i + 0] * xv[4 * i + 0] + xv[4 * i + 1] * xv[4 * i + 1] +
          xv[4 * i + 2] * xv[4 * i + 2] + xv[4 * i + 3] * xv[4 * i + 3];
  }
  __shared__ float red[2][4];
  const int lane = t & 63, wv = t >> 6;
#pragma unroll
  for (int off = 32; off; off >>= 1) { s += __shfl_down(s, off); ss += __shfl_down(ss, off); }
  if (lane == 0) { red[0][wv] = s; red[1][wv] = ss; }
  __syncthreads();
  s  = red[0][0] + red[0][1] + red[0][2] + red[0][3];
  ss = red[1][0] + red[1][1] + red[1][2] + red[1][3];
  const float mu = s * (1.f / H_);
  const float var = ss * (1.f / H_) - mu * mu;
  const float rstd = rsqrtf(var + EPS_);
  const float g = 1.f / (1.f + __expf(-gate_logit[0]));
#pragma unroll
  for (int i = 0; i < 4; ++i) {
    float4 wv4 = ((const float4*)w)[t + 256 * i];
    float4 bv4 = ((const float4*)bvec)[t + 256 * i];
    float4 ov;
    ov.x = hv[i].x + g * ((xv[4 * i + 0] - mu) * rstd * wv4.x + bv4.x - hv[i].x);
    ov.y = hv[i].y + g * ((xv[4 * i + 1] - mu) * rstd * wv4.y + bv4.y - hv[i].y);
    ov.z = hv[i].z + g * ((xv[4 * i + 2] - mu) * rstd * wv4.z + bv4.z - hv[i].z);
    ov.w = hv[i].w + g * ((xv[4 * i + 3] - mu) * rstd * wv4.w + bv4.w - hv[i].w);
    ((float4*)o)[t + 256 * i] = ov;
  }
}

// ---------------------------------------------------------------- launcher
extern "C" void kernel_launch(void* const* d_in, const int* in_sizes, int n_in,
                              void* d_out, int out_size, void* d_ws, size_t ws_size,
                              hipStream_t stream) {
  const float* hidden = (const float*)d_in[0];
  const float* mem    = (const float*)d_in[1];
  const unsigned char* mask = (const unsigned char*)d_in[2];
  const float* Wq = (const float*)d_in[3];
  const float* bq = (const float*)d_in[4];
  const float* Wk = (const float*)d_in[5];
  const float* bk = (const float*)d_in[6];
  const float* Wv = (const float*)d_in[7];
  const float* bv = (const float*)d_in[8];
  const float* Wo = (const float*)d_in[9];
  const float* bo = (const float*)d_in[10];
  const float* lnw1 = (const float*)d_in[11];
  const float* lnb1 = (const float*)d_in[12];
  const float* lnw2 = (const float*)d_in[13];
  const float* lnb2 = (const float*)d_in[14];
  const float* gate = (const float*)d_in[15];
  float* out = (float*)d_out;

  // workspace layout (f16 elements)
  _Float16* p = (_Float16*)d_ws;
  _Float16* hnorm = p; p += (size_t)8192 * H_;        // 67.1 MB; later: attn fp32 partials (50.3 MB), then ctx_h
  _Float16* Qh    = p; p += (size_t)8192 * A_;        // 8.4 MB
  _Float16* memh  = p; p += (size_t)6000 * D_;        // 12.3 MB
  _Float16* WqT   = p; p += (size_t)A_ * H_;          // [A][H]
  _Float16* WkT   = p; p += (size_t)A_ * D_;          // [A][D] (dead after qkv -> lsum alias)
  _Float16* WvT   = p; p += (size_t)A_ * D_;
  _Float16* WoT   = p; p += (size_t)H_ * A_;          // [H][A]
  _Float16* Kp    = p; p += (size_t)B_ * TMP_ * A_;   // [B][1536][512]
  _Float16* VT    = p; p += (size_t)B_ * A_ * TMP_;   // [B][512][1536]
  _Float16* sc    = p; p += (size_t)B_ * LQ_ * TMP_;  // [B][2048][1536] exp-scores
  _Float16* ctx   = p; p += (size_t)8192 * A_;        // [8192][512]
  // aliases (disjoint lifetimes):
  float* Qpart = (float*)sc;      // 2 x 8192 x 512 fp32 = 33.55 MB == sizeof(sc)+sizeof(ctx)
  float* Apart = (float*)hnorm;   // 3 x 4 x 2048 x 512 fp32 = 50.3 MB <= 67.1 MB
  float* lsum  = (float*)WkT;     // 8192 fp32 = 32 KB; WkT dead after qkv; zeroed in qreduce

  // 1. prep: LN1 + mem->f16 + 4 weight transposes (one dispatch)
  prep_kernel<<<8192 + 1500 + 2048 + 512 + 512 + 2048, 256, 0, stream>>>(
      hidden, lnw1, lnb1, hnorm, mem, memh, Wq, WqT, Wk, WkT, Wv, WvT, Wo, WoT);
  // 2. fused Q(split-K x2) + K + V projections: 896 blocks (~3.5/CU)
  qkv_kernel<<<896, 256, 0, stream>>>(hnorm, WqT, Qpart, memh, WkT, bk, Kp, WvT, bv, VT);
  // 3. Q = sum partials + bq -> f16; tail blocks zero lsum
  qreduce_kernel<<<4096 + 32, 256, 0, stream>>>(Qpart, bq, Qh, lsum);
  // 4. exp-scores = exp(Q @ K^T / sqrt(A)) with mask/pad zeroing + row sums
  scores_kernel<<<dim3(12, 16, 4), 256, 0, stream>>>(Qh, Kp, sc, mask, lsum);
  // 5. ctx partials = exp-scores @ V, split-K x3 (K=512 each): 768 blocks
  gemm_nt_kernel<2><<<dim3(4, 16, 12), 256, 0, stream>>>(
      sc, (size_t)LQ_ * TMP_, TMP_, VT, (size_t)A_ * TMP_, TMP_, nullptr,
      (void*)Apart, (size_t)LQ_ * A_, (size_t)B_ * LQ_ * A_, A_, LQ_, 16, 3, 512, 1.f);
  // 6. ctx = (sum partials) / lsum -> f16
  areduce_kernel<<<4096, 256, 0, stream>>>(Apart, lsum, ctx);
  // 7. ctx_h = ctx @ Wo + bo -> reuse hnorm buffer  [8192][4096] (2048 blocks)
  gemm_nt_kernel<0><<<dim3(32, 64, 1), 256, 0, stream>>>(
      ctx, 0, A_, WoT, 0, A_, bo, (void*)hnorm, 0, 0, H_, 8192, 16, 1, 0, 1.f);
  // 8. out = hidden + g*(LN(hidden+ctx_h) - hidden)
  ln2_gate_kernel<<<8192, 256, 0, stream>>>(hidden, hnorm, lnw2, lnb2, gate, out);
}